// Round 7
// baseline (262.466 us; speedup 1.0000x reference)
//
#include <hip/hip_runtime.h>
#include <hip/hip_bf16.h>

#define D_MODEL 4096
#define NTOK    8192   // B*S = 4*2048
#define SEQ     2048

typedef short bf16x8 __attribute__((ext_vector_type(8)));  // 8 bf16 in 4 VGPRs
typedef float f32x4  __attribute__((ext_vector_type(4)));

typedef const __attribute__((address_space(1))) char* gas1_t;
typedef __attribute__((address_space(3))) char* las3_t;

__device__ inline void async16(const void* g, void* l) {
  // direct global->LDS DMA, 16 B/lane; LDS dest = wave-uniform base + lane*16
  __builtin_amdgcn_global_load_lds((gas1_t)g, (las3_t)l, 16, 0, 0);
}

__device__ inline short f2bf(float x) {
  __hip_bfloat16 h = __float2bfloat16(x);
  return *reinterpret_cast<short*>(&h);
}
__device__ inline float bf2f(const void* p, size_t i) {
  return __bfloat162float(((const __hip_bfloat16*)p)[i]);
}

// ---------------------------------------------------------------------------
// Kernel 0: dtype sniffing (confirmed: hidden=bf16, weights=f32; kept for
// robustness). flag=1 -> read as bf16[], flag=0 -> read as float[].
// ---------------------------------------------------------------------------
__global__ __launch_bounds__(320) void sniff_k(const void* hid, const void* wf,
                                               const void* w1, const void* w2,
                                               const void* b1, const void* b2,
                                               const void* lam,
                                               int* flags, float* scal) {
  int wv = threadIdx.x >> 6, lane = threadIdx.x & 63;
  const unsigned short* p = nullptr;
  int n = 0;
  switch (wv) {
    case 0: p = (const unsigned short*)hid; n = NTOK * D_MODEL; break;
    case 1: p = (const unsigned short*)wf;  n = 16 * D_MODEL;   break;
    case 2: p = (const unsigned short*)w1;  n = 64 * 4112;      break;
    case 3: p = (const unsigned short*)w2;  n = 64;             break;
    case 4: p = (const unsigned short*)b1;  n = 64;             break;
  }
  int S = n / 2 < 64 ? n / 2 : 64;
  bool act = lane < S;
  unsigned short ve = 0, vo = 0;
  if (act) { ve = p[2 * lane]; vo = p[2 * lane + 1]; }
  int ee = (ve >> 7) & 0xFF, eo = (vo >> 7) & 0xFF;
  bool ve_band   = (ve == 0) || (ve == 0x8000) || (ee >= 96 && ee <= 141);
  bool vo_bandnz = (vo != 0) && (vo != 0x8000) && (eo >= 96 && eo <= 141);
  int zp = __popcll(__ballot(act && ve == 0 && vo == 0));
  int ob = __popcll(__ballot(act && ve == 0 && vo_bandnz));
  int eb = __popcll(__ballot(act && ve_band));
  if (lane == 0) {
    int f;
    if (zp == S) f = 1;
    else if (4 * ob >= 3 * S) f = 0;    // f32 storage of bf16-rounded values
    else if (4 * eb >= 3 * S) f = 1;    // true bf16
    else f = 0;                         // raw f32
    flags[wv] = f;
  }
  if (threadIdx.x == 0) {
    unsigned short l0 = *(const unsigned short*)lam;
    int le = (l0 >> 7) & 0xFF;
    if (l0 != 0 && l0 != 0x8000 && le >= 96 && le <= 141)
      scal[0] = __bfloat162float(*(const __hip_bfloat16*)lam);
    else
      scal[0] = *(const float*)lam;
    unsigned short c0 = *(const unsigned short*)b2;
    int ce = (c0 >> 7) & 0xFF;
    if (c0 == 0) scal[1] = 0.0f;
    else if (c0 != 0x8000 && ce >= 96 && ce <= 141)
      scal[1] = __bfloat162float(*(const __hip_bfloat16*)b2);
    else
      scal[1] = *(const float*)b2;
  }
}

// ---------------------------------------------------------------------------
// Kernel 1: fold W_fiber into W1 -> W1_eff[64][4096] bf16 (internal format).
// ---------------------------------------------------------------------------
__global__ __launch_bounds__(256) void fold_w1(const void* __restrict__ W1v,
                                               const void* __restrict__ Wfv,
                                               const int* __restrict__ flags,
                                               __hip_bfloat16* __restrict__ W1eff) {
  int n = blockIdx.x;  // 0..63
  int fw1 = flags[2], fwf = flags[1];
  __shared__ float w1b[16];
  if (threadIdx.x < 16) {
    size_t idx = (size_t)n * 4112 + 4096 + threadIdx.x;
    w1b[threadIdx.x] = fw1 ? bf2f(W1v, idx) : ((const float*)W1v)[idx];
  }
  __syncthreads();
  for (int k = threadIdx.x; k < D_MODEL; k += 256) {
    size_t idx = (size_t)n * 4112 + k;
    float v = fw1 ? bf2f(W1v, idx) : ((const float*)W1v)[idx];
#pragma unroll
    for (int f = 0; f < 16; ++f) {
      size_t wi = (size_t)f * D_MODEL + k;
      float wfv = fwf ? bf2f(Wfv, wi) : ((const float*)Wfv)[wi];
      v += w1b[f] * wfv;
    }
    W1eff[(size_t)n * D_MODEL + k] = __float2bfloat16(v);
  }
}

// ---------------------------------------------------------------------------
// Kernel 2: split-K GEMM partials (raw z, pre-GELU). m97-style staging.
// Grid 1024 = 256 M-tiles(32 rows) x 4 K-quarters (blockIdx = t*4 + q).
// Block 512 thr = 8 waves; LDS 48 KB (A 16K + B 32K, unpadded 512B rows)
// -> 3 blocks/CU co-resident = 24 waves/CU (cross-block overlap hides the
// per-chunk barrier drain -- the m114 mechanism R6 lacked).
// Staging: FULL-wave unmasked global_load_lds, 1 KB/instr (2 rows). Bank
// conflicts avoided by XOR-swizzling the GLOBAL source slot: logical 16B
// slot s of row r is fetched from global slot s^(r&7), so physical LDS
// slot s holds logical slot s^(r&7); readers apply the same XOR. Global
// access stays coalesced (permutation within 128B groups).
// Per chunk (256 k): each wave stages 6 DMAs (A rows 4w..4w+3, B rows
// 8w..8w+7), syncthreads, computes its (rg=w&1, kq=w>>1) slice: 2 ksteps
// x 4 n-regs MFMA 16x16x32 bf16. C: col=lane&15, row=(lane>>4)*4+reg.
// Epilogue: LDS reduce over kq -> part[q][tok][64] f32 (GELU is nonlinear,
// so K-split partials must stay raw).
// ---------------------------------------------------------------------------
__global__ __launch_bounds__(512, 6) void gemm_part(const void* __restrict__ hid,
                                                    const short* __restrict__ B_,
                                                    const int* __restrict__ flags,
                                                    float* __restrict__ part) {
  __shared__ short SMEM[24576];      // 48 KB: A [32][256] | B [64][256]
  short* As = SMEM;
  short* Bs = SMEM + 8192;
  int t = blockIdx.x >> 2;           // M-tile 0..255 (rows t*32..t*32+31)
  int q = blockIdx.x & 3;            // K-quarter 0..3 (1024 k each)
  int tid = threadIdx.x;
  int w = tid >> 6, lane = tid & 63;
  int m = lane & 15, kg = lane >> 4;
  int rg = w & 1, kq = w >> 1;
  int rdma = lane >> 5;              // 0/1: which of the 2 rows this lane stages
  int sdma = lane & 31;              // 16B slot within row
  f32x4 acc[4];
#pragma unroll
  for (int g = 0; g < 4; ++g) acc[g] = (f32x4){0.f, 0.f, 0.f, 0.f};

  const short* hidA = (const short*)hid;
  int fhid = flags[0];

#pragma unroll 1
  for (int c = 0; c < 4; ++c) {
    int kbase = q * 1024 + c * 256;  // in shorts
    if (fhid) {
      // A: 2 instrs/wave, rows 4w..4w+3
#pragma unroll
      for (int i = 0; i < 2; ++i) {
        int r0 = w * 4 + i * 2;
        int r  = r0 + rdma;
        const short* gp = hidA + (size_t)(t * 32 + r) * D_MODEL + kbase +
                          ((sdma ^ (r & 7)) * 8);
        async16(gp, As + r0 * 256);  // uniform base; lane lands at r*512B+s*16B
      }
    } else {
      // f32 fallback: manual convert+swizzled store
      for (int e = tid; e < 32 * 256; e += 512) {
        int r = e >> 8, k = e & 255;
        float v = ((const float*)hid)[(size_t)(t * 32 + r) * D_MODEL + kbase + k];
        As[r * 256 + (((k >> 3) ^ (r & 7)) * 8) + (k & 7)] = f2bf(v);
      }
    }
    // B: 4 instrs/wave, rows 8w..8w+7
#pragma unroll
    for (int i = 0; i < 4; ++i) {
      int r0 = w * 8 + i * 2;
      int r  = r0 + rdma;
      const short* gp = B_ + (size_t)r * D_MODEL + kbase + ((sdma ^ (r & 7)) * 8);
      async16(gp, Bs + r0 * 256);
    }
    __syncthreads();   // compiler-inserted vmcnt(0): DMA visible
#pragma unroll
    for (int j = 0; j < 2; ++j) {
      int sl  = kq * 8 + j * 4 + kg;         // logical 16B slot in chunk
      int off = ((sl ^ (m & 7)) * 8);        // physical (swizzled) short offset
      bf16x8 a   = *(const bf16x8*)(As + (rg * 16 + m) * 256 + off);
      bf16x8 b0v = *(const bf16x8*)(Bs + (m +  0) * 256 + off);
      bf16x8 b1v = *(const bf16x8*)(Bs + (m + 16) * 256 + off);
      bf16x8 b2v = *(const bf16x8*)(Bs + (m + 32) * 256 + off);
      bf16x8 b3v = *(const bf16x8*)(Bs + (m + 48) * 256 + off);
      acc[0] = __builtin_amdgcn_mfma_f32_16x16x32_bf16(a, b0v, acc[0], 0, 0, 0);
      acc[1] = __builtin_amdgcn_mfma_f32_16x16x32_bf16(a, b1v, acc[1], 0, 0, 0);
      acc[2] = __builtin_amdgcn_mfma_f32_16x16x32_bf16(a, b2v, acc[2], 0, 0, 0);
      acc[3] = __builtin_amdgcn_mfma_f32_16x16x32_bf16(a, b3v, acc[3], 0, 0, 0);
    }
    __syncthreads();   // all reads done before restaging
  }

  // ---- reduce over kq (4 quarters) in LDS -> part[q][tok][64] ----
  float* red = (float*)SMEM;  // [4][32][64] f32 = 32 KB (aliases A+B)
#pragma unroll
  for (int g = 0; g < 4; ++g)
#pragma unroll
    for (int r = 0; r < 4; ++r)
      red[((kq * 32) + (rg * 16 + kg * 4 + r)) * 64 + (g * 16 + m)] = acc[g][r];
  __syncthreads();
  int row = tid >> 4, cid = tid & 15;
  float* po = part + ((size_t)q * NTOK + (size_t)t * 32 + row) * 64;
#pragma unroll
  for (int j = 0; j < 4; ++j) {
    int col = cid + 16 * j;
    float s = red[(0 * 32 + row) * 64 + col] + red[(1 * 32 + row) * 64 + col] +
              red[(2 * 32 + row) * 64 + col] + red[(3 * 32 + row) * 64 + col];
    po[col] = s;
  }
}

// ---------------------------------------------------------------------------
// Kernel 3: reduce 4 K-quarter partials + b1, exact GELU, dot W2, softplus.
// Grid 512 x 256 thr: 16 tokens/block; thread = (token 0..15) x (cid 0..15).
// ---------------------------------------------------------------------------
__global__ __launch_bounds__(256) void delta_ep(const float* __restrict__ part,
                                                const void* __restrict__ b1,
                                                const void* __restrict__ w2,
                                                const int* __restrict__ flags,
                                                const float* __restrict__ scal,
                                                float* __restrict__ delta) {
  int tok = blockIdx.x * 16 + (threadIdx.x >> 4);
  int cid = threadIdx.x & 15;
  int fb1 = flags[4], fw2 = flags[3];
  float y = 0.f;
#pragma unroll
  for (int j = 0; j < 4; ++j) {
    int col = cid + 16 * j;
    float s = 0.f;
#pragma unroll
    for (int c = 0; c < 4; ++c)
      s += part[((size_t)c * NTOK + tok) * 64 + col];
    s += fb1 ? bf2f(b1, col) : ((const float*)b1)[col];
    float g = 0.5f * s * (1.0f + erff(s * 0.70710678118654752f));  // exact GELU
    y += g * (fw2 ? bf2f(w2, col) : ((const float*)w2)[col]);
  }
#pragma unroll
  for (int off = 1; off <= 8; off <<= 1) y += __shfl_xor(y, off, 64);
  if (cid == 0) {
    float x = y + scal[1];  // + b2
    delta[tok] = (x > 20.0f) ? x : log1pf(expf(x));  // softplus
  }
}

// ---------------------------------------------------------------------------
// Kernel 4: causal EMA, gate, field, mean. OUTPUT IS FLOAT32 (mixed tuple
// (bf16,bf16,f32) concatenated by harness -> numpy-promoted f32).
// ---------------------------------------------------------------------------
__global__ __launch_bounds__(256) void ema_out(const float* __restrict__ delta,
                                               const float* __restrict__ scal,
                                               float* __restrict__ out) {
  int b    = threadIdx.x >> 6;   // batch 0..3
  int lane = threadIdx.x & 63;
  const float alpha = 0.9f;
  float d[32];
  const float* dp = delta + b * SEQ + lane * 32;
  float beta = 0.f, lsum = 0.f;
#pragma unroll
  for (int i = 0; i < 32; ++i) {
    d[i] = dp[i];
    lsum += d[i];
    beta = alpha * beta + 0.1f * d[i];
  }
  float accA = 0.03433683820292512f;  // 0.9^32
  float accB = beta;
  for (int off = 1; off < 64; off <<= 1) {
    float uA = __shfl_up(accA, off, 64);
    float uB = __shfl_up(accB, off, 64);
    if (lane >= off) {
      accB = accB + accA * uB;  // cur o prev
      accA = accA * uA;
    }
  }
  float prev = __shfl_up(accB, 1, 64);
  float h = (lane == 0) ? 0.f : prev;  // carry-in state for this chunk
  float lam = scal[0];
#pragma unroll
  for (int i = 0; i < 32; ++i) {
    h = alpha * h + 0.1f * d[i];
    float gate = 1.0f / (1.0f + expf(lam * h));  // sigmoid(-lam*h)
    out[b * SEQ + lane * 32 + i]        = gate;
    out[NTOK + b * SEQ + lane * 32 + i] = h;
  }
#pragma unroll
  for (int off = 32; off >= 1; off >>= 1) lsum += __shfl_xor(lsum, off, 64);
  __shared__ float bs[4];
  if (lane == 0) bs[b] = lsum;
  __syncthreads();
  if (threadIdx.x == 0)
    out[2 * NTOK] = (bs[0] + bs[1] + bs[2] + bs[3]) * (1.0f / 8192.0f);
}

// ---------------------------------------------------------------------------
extern "C" void kernel_launch(void* const* d_in, const int* in_sizes, int n_in,
                              void* d_out, int out_size, void* d_ws, size_t ws_size,
                              hipStream_t stream) {
  const void* hidden = d_in[0];  // [4,2048,4096]
  const void* Wf     = d_in[1];  // [16,4096]
  const void* W1     = d_in[2];  // [64,4112]
  const void* b1     = d_in[3];  // [64]
  const void* W2     = d_in[4];  // [1,64]
  const void* b2     = d_in[5];  // [1]
  const void* lam    = d_in[6];  // [1]
  float* out = (float*)d_out;    // 16385 f32 (gate 8192 | field 8192 | mean 1)

  // ws: [0,32) flags, [32,64) scal, [64,+512K) W1eff bf16, [+32K) delta f32,
  // then part f32 [4][8192][64] = 8 MB. Total ~8.6 MB.
  char* ws = (char*)d_ws;
  int*   flags = (int*)ws;
  float* scal  = (float*)(ws + 32);
  __hip_bfloat16* W1eff = (__hip_bfloat16*)(ws + 64);
  float* delta = (float*)(ws + 64 + (size_t)64 * D_MODEL * 2);
  float* part  = (float*)(ws + 64 + (size_t)64 * D_MODEL * 2 + NTOK * 4);

  sniff_k<<<1, 320, 0, stream>>>(hidden, Wf, W1, W2, b1, b2, lam, flags, scal);
  fold_w1<<<64, 256, 0, stream>>>(W1, Wf, flags, W1eff);
  gemm_part<<<1024, 512, 0, stream>>>(hidden, (const short*)W1eff, flags, part);
  delta_ep<<<512, 256, 0, stream>>>(part, b1, W2, flags, scal, delta);
  ema_out<<<1, 256, 0, stream>>>(delta, scal, out);
}